// Round 3
// baseline (199.960 us; speedup 1.0000x reference)
//
#include <hip/hip_runtime.h>

// ---------------------------------------------------------------------------
// GeometricRound: geo(Clifford Cl(3) pairwise) -> mix -> LayerNorm -> MLP
// (gate/up 128->512, silu*mul, down 512->128) -> +x residual.
// B=4 T=4096 N=8 D=128 F=512.  M = B*T*N = 131072 rows.
//
// 3 dispatches:
//  k_prep    : sigmoid-combine interaction weights -> 36 coeffs; bf16-convert
//              + transpose + XOR-swizzle w_gate/w_up/w_down into d_ws.
//  k_geo_ln  : geo + mix + LN per row; writes normed (bf16) into the first
//              256 B of each 512 B d_out row (block-private, overwritten later).
//  k_mlp     : per block 128 rows; bf16 MFMA 16x16x32, both GEMMs operand-
//              swapped; weights staged via global_load_lds; h transposed via
//              swizzled LDS; f32 accum; residual epilogue.
// ---------------------------------------------------------------------------

typedef __bf16 bf16x8 __attribute__((ext_vector_type(8)));
typedef float  f32x4  __attribute__((ext_vector_type(4)));

#define MFMA16(a, b, c) __builtin_amdgcn_mfma_f32_16x16x32_bf16((a), (b), (c), 0, 0, 0)

// d_ws layout (bytes)
constexpr int OFF_WG = 0;        // 8 chunks x 16 KiB  (w_gate, [f][k] swizzled)
constexpr int OFF_WU = 131072;   // 8 chunks x 16 KiB  (w_up)
constexpr int OFF_WD = 262144;   // 8 chunks x 16 KiB  (w_down, [d][f] swizzled)
constexpr int OFF_C  = 393216;   // 38 f32: 36 geo coeffs, gate, 1-gate

// ---- small helpers --------------------------------------------------------

__device__ __forceinline__ float fexp2(float x) {
  float r; asm("v_exp_f32 %0, %1" : "=v"(r) : "v"(x)); return r;
}
__device__ __forceinline__ float frcp(float x) {
  float r; asm("v_rcp_f32 %0, %1" : "=v"(r) : "v"(x)); return r;
}
__device__ __forceinline__ float fsigmoid(float x) {
  return frcp(1.f + fexp2(-1.44269504088896f * x));
}
// f32 -> bf16 (RNE), returns low 16 bits
__device__ __forceinline__ unsigned cvtbf(float f) {
  unsigned u = __builtin_bit_cast(unsigned, f);
  return (u + 0x7fffu + ((u >> 16) & 1u)) >> 16;
}
__device__ __forceinline__ unsigned pack2(float a, float b) {
  return cvtbf(a) | (cvtbf(b) << 16);
}

// unordered pair table for geo basis indices k=1..7 (4 pairs each)
// re-derived from _reduce_product: e_i^2=+1, each adjacent swap = -1
__device__ constexpr int PIdx[7][4][2] = {
  {{0,1},{2,4},{3,5},{6,7}},   // k=1 (e1)
  {{0,2},{1,4},{3,6},{5,7}},   // k=2 (e2)
  {{0,3},{1,5},{2,6},{4,7}},   // k=3 (e3)
  {{0,4},{1,2},{3,7},{5,6}},   // k=4 (e12)
  {{0,5},{1,3},{2,7},{4,6}},   // k=5 (e13)
  {{0,6},{1,7},{2,3},{4,5}},   // k=6 (e23)
  {{0,7},{1,6},{2,5},{3,4}}};  // k=7 (e123)

// ---- kernel 0: prep -------------------------------------------------------
// 768 blocks x 256 threads = 196608 = 3 * 128*512 weight elements.
__global__ __launch_bounds__(256) void k_prep(
    const float* __restrict__ W,   // (8,8) interaction
    const float* __restrict__ wg,  // (128,512)
    const float* __restrict__ wu,  // (128,512)
    const float* __restrict__ wd,  // (512,128)
    const float* __restrict__ gg,  // scalar geo_gate
    char* __restrict__ ws) {
  int gid = blockIdx.x * 256 + threadIdx.x;
  if (gid < 65536) {                       // w_gate: idx = k*512 + f (read-coalesced over f)
    int f = gid & 511, k = gid >> 9;
    unsigned short v = (unsigned short)cvtbf(wg[k * 512 + f]);
    int fl = f & 63;
    int off = OFF_WG + (f >> 6) * 16384 + (((fl * 256 + k * 2)) ^ ((f & 7) << 4));
    *(unsigned short*)(ws + off) = v;
  } else if (gid < 131072) {               // w_up
    int t = gid - 65536;
    int f = t & 511, k = t >> 9;
    unsigned short v = (unsigned short)cvtbf(wu[k * 512 + f]);
    int fl = f & 63;
    int off = OFF_WU + (f >> 6) * 16384 + (((fl * 256 + k * 2)) ^ ((f & 7) << 4));
    *(unsigned short*)(ws + off) = v;
  } else {                                 // w_down: idx = f*128 + d (read-coalesced over d)
    int t = gid - 131072;
    int d = t & 127, f = t >> 7;
    unsigned short v = (unsigned short)cvtbf(wd[f * 128 + d]);
    int fl = f & 63;
    int off = OFF_WD + (f >> 6) * 16384 + (((d * 128 + fl * 2)) ^ ((d & 7) << 4));
    *(unsigned short*)(ws + off) = v;
  }
  if (blockIdx.x == 0 && threadIdx.x == 0) {
    float s[64];
    for (int i = 0; i < 64; ++i) s[i] = fsigmoid(W[i]);
    float* C = (float*)(ws + OFF_C);
#define Sij(i, j) s[(i) * 8 + (j)]
    // k=0: diagonal, signs + + + + - - - -
    for (int i = 0; i < 8; ++i) C[i] = (i < 4 ? 1.f : -1.f) * Sij(i, i);
    // k=1..7: combined coefficient per unordered pair (signs from Cl(3) table)
    C[8]  =  Sij(0,1) + Sij(1,0);  C[9]  = -Sij(2,4) + Sij(4,2);
    C[10] = -Sij(3,5) + Sij(5,3);  C[11] = -Sij(6,7) - Sij(7,6);
    C[12] =  Sij(0,2) + Sij(2,0);  C[13] =  Sij(1,4) - Sij(4,1);
    C[14] = -Sij(3,6) + Sij(6,3);  C[15] =  Sij(5,7) + Sij(7,5);
    C[16] =  Sij(0,3) + Sij(3,0);  C[17] =  Sij(1,5) - Sij(5,1);
    C[18] =  Sij(2,6) - Sij(6,2);  C[19] = -Sij(4,7) - Sij(7,4);
    C[20] =  Sij(0,4) + Sij(4,0);  C[21] =  Sij(1,2) - Sij(2,1);
    C[22] =  Sij(3,7) + Sij(7,3);  C[23] = -Sij(5,6) + Sij(6,5);
    C[24] =  Sij(0,5) + Sij(5,0);  C[25] =  Sij(1,3) - Sij(3,1);
    C[26] = -Sij(2,7) - Sij(7,2);  C[27] =  Sij(4,6) - Sij(6,4);
    C[28] =  Sij(0,6) + Sij(6,0);  C[29] =  Sij(1,7) + Sij(7,1);
    C[30] =  Sij(2,3) - Sij(3,2);  C[31] = -Sij(4,5) + Sij(5,4);
    C[32] =  Sij(0,7) + Sij(7,0);  C[33] =  Sij(1,6) + Sij(6,1);
    C[34] = -Sij(2,5) - Sij(5,2);  C[35] =  Sij(3,4) + Sij(4,3);
#undef Sij
    float gate = fsigmoid(gg[0]);
    C[36] = gate; C[37] = 1.f - gate;
  }
}

// ---- kernel 1: geo + mix + LN --------------------------------------------
// 4096 blocks x 256 threads; wave w handles bt = blk*4+w; lane l owns d=2l,2l+1.
__global__ __launch_bounds__(256) void k_geo_ln(
    const float* __restrict__ x,
    const float* __restrict__ gamma,
    const float* __restrict__ beta,
    const float* __restrict__ cws,
    unsigned* __restrict__ outw) {       // d_out viewed as u32 words
  const int tid = threadIdx.x, l = tid & 63, w = tid >> 6;
  const long bt = (long)blockIdx.x * 4 + w;
  const long row0 = bt * 8;

  float C[38];
#pragma unroll
  for (int i = 0; i < 38; ++i) C[i] = cws[i];  // uniform -> s_loads
  const float gate = C[36], omg = C[37];

  float2 gm = *(const float2*)(gamma + 2 * l);
  float2 be = *(const float2*)(beta + 2 * l);

  float xa[8], xb[8];
#pragma unroll
  for (int n = 0; n < 8; ++n) {
    float2 v = *(const float2*)(x + (size_t)(row0 + n) * 128 + 2 * l);
    xa[n] = v.x; xb[n] = v.y;
  }

  float ga[8], gb[8];
  {
    float a0 = C[0] * xa[0] * xa[0], b0 = C[0] * xb[0] * xb[0];
#pragma unroll
    for (int i = 1; i < 8; ++i) {
      a0 = fmaf(C[i], xa[i] * xa[i], a0);
      b0 = fmaf(C[i], xb[i] * xb[i], b0);
    }
    ga[0] = a0; gb[0] = b0;
#pragma unroll
    for (int k = 1; k < 8; ++k) {
      float ta = 0.f, tb = 0.f;
#pragma unroll
      for (int p = 0; p < 4; ++p) {
        const int i = PIdx[k - 1][p][0], j = PIdx[k - 1][p][1];
        const float c = C[8 + (k - 1) * 4 + p];
        ta = fmaf(c, xa[i] * xa[j], ta);
        tb = fmaf(c, xb[i] * xb[j], tb);
      }
      ga[k] = ta; gb[k] = tb;
    }
  }

  float ma[8], mb[8], s[8], ss[8];
#pragma unroll
  for (int n = 0; n < 8; ++n) {
    ma[n] = fmaf(gate, ga[n], omg * xa[n]);
    mb[n] = fmaf(gate, gb[n], omg * xb[n]);
    s[n]  = ma[n] + mb[n];
    ss[n] = fmaf(ma[n], ma[n], mb[n] * mb[n]);
  }
  // 16 simultaneous 64-lane butterfly reductions
#pragma unroll
  for (int st = 0; st < 6; ++st) {
    const int off = 1 << st;
#pragma unroll
    for (int n = 0; n < 8; ++n) {
      s[n]  += __shfl_xor(s[n], off);
      ss[n] += __shfl_xor(ss[n], off);
    }
  }
#pragma unroll
  for (int n = 0; n < 8; ++n) {
    float mean = s[n] * (1.f / 128.f);
    float var  = fmaf(-mean, mean, ss[n] * (1.f / 128.f));
    float rstd = rsqrtf(var + 1e-5f);
    float na = fmaf((ma[n] - mean) * rstd, gm.x, be.x);
    float nb = fmaf((mb[n] - mean) * rstd, gm.y, be.y);
    outw[(size_t)(row0 + n) * 128 + l] = pack2(na, nb);  // bytes row*512 + 4l
  }
}

// ---- kernel 2: MLP via MFMA ----------------------------------------------
// 1024 blocks x 256 threads (4 waves). Block owns 128 rows, wave owns 32.
__global__ __launch_bounds__(256, 2) void k_mlp(
    const float* __restrict__ x,
    float* __restrict__ out,
    const char* __restrict__ ws) {
  __shared__ __align__(16) char lds[65536];  // 48K weight chunks + 4x4K h_t
  const int tid = threadIdx.x, l = tid & 63, w = tid >> 6;
  const int r16 = l & 15, g4 = l >> 4;
  const long rows_base = (long)blockIdx.x * 128;
  const long wrow0 = rows_base + w * 32;

  // normed B-fragments (B[k][row]): lane: row=l&15, k=g4*8+e  -- direct, coalesced
  const char* outb = (const char*)out;
  bf16x8 bn[2][4];
#pragma unroll
  for (int rt = 0; rt < 2; ++rt)
#pragma unroll
    for (int ks = 0; ks < 4; ++ks) {
      const uint4 v = *(const uint4*)(outb + (wrow0 + rt * 16 + r16) * 512 +
                                      (ks * 32 + g4 * 8) * 2);
      bn[rt][ks] = __builtin_bit_cast(bf16x8, v);
    }

  f32x4 acc[8][2];
#pragma unroll
  for (int dt = 0; dt < 8; ++dt)
#pragma unroll
    for (int rt = 0; rt < 2; ++rt) acc[dt][rt] = f32x4{0.f, 0.f, 0.f, 0.f};

  const char* lwg = lds;
  const char* lwu = lds + 16384;
  const char* lwd = lds + 32768;
  char* lht = lds + 49152 + w * 4096;  // per-wave h transpose [32][64] bf16, swizzled

  for (int fc = 0; fc < 8; ++fc) {
    __syncthreads();  // previous chunk's LDS readers done
    // stage 48 KiB: wg, wu, wd chunk slabs (pre-swizzled in ws -> linear copy)
#pragma unroll
    for (int j = 0; j < 12; ++j) {
      int o = (w * 12 + j) * 1024 + l * 16;
      const char* src = ws + (o >> 14) * 131072 + fc * 16384 + (o & 16383);
      __builtin_amdgcn_global_load_lds(
          (const __attribute__((address_space(1))) unsigned*)src,
          (__attribute__((address_space(3))) unsigned*)(lds + (w * 12 + j) * 1024),
          16, 0, 0);
    }
    __syncthreads();  // staged data visible

    // GEMM1 (swapped): C'[f][row] = Wg[f][k] x normed[row][k]
#pragma unroll
    for (int ft = 0; ft < 4; ++ft) {
      const int fl = ft * 16 + r16, swzf = (fl & 7) << 4;
      bf16x8 ag[4], au[4];
#pragma unroll
      for (int ks = 0; ks < 4; ++ks) {
        const int kb = (ks * 32 + g4 * 8) * 2;
        ag[ks] = *(const bf16x8*)(lwg + fl * 256 + (kb ^ swzf));
        au[ks] = *(const bf16x8*)(lwu + fl * 256 + (kb ^ swzf));
      }
#pragma unroll
      for (int rt = 0; rt < 2; ++rt) {
        f32x4 cg = {0.f, 0.f, 0.f, 0.f}, cu = {0.f, 0.f, 0.f, 0.f};
#pragma unroll
        for (int ks = 0; ks < 4; ++ks) {
          cg = MFMA16(ag[ks], bn[rt][ks], cg);
          cu = MFMA16(au[ks], bn[rt][ks], cu);
        }
        float h0 = cg[0] * cu[0] * frcp(1.f + fexp2(-1.44269504f * cg[0]));
        float h1 = cg[1] * cu[1] * frcp(1.f + fexp2(-1.44269504f * cg[1]));
        float h2 = cg[2] * cu[2] * frcp(1.f + fexp2(-1.44269504f * cg[2]));
        float h3 = cg[3] * cu[3] * frcp(1.f + fexp2(-1.44269504f * cg[3]));
        uint2 hv; hv.x = pack2(h0, h1); hv.y = pack2(h2, h3);
        const int row_l = rt * 16 + r16;
        const int fb = (ft * 16 + g4 * 4) * 2;  // 4 consecutive f per lane -> b64
        *(uint2*)(lht + row_l * 128 + (fb ^ ((row_l & 7) << 4))) = hv;
      }
    }

    // GEMM2 (swapped): out'[d][row] += Wd[d][f] x h[row][f]   (per-wave h_t)
    bf16x8 hb[2][2];
#pragma unroll
    for (int rt = 0; rt < 2; ++rt)
#pragma unroll
      for (int ks2 = 0; ks2 < 2; ++ks2) {
        const int row_l = rt * 16 + r16;
        const int fb = (ks2 * 32 + g4 * 8) * 2;
        hb[rt][ks2] = *(const bf16x8*)(lht + row_l * 128 + (fb ^ ((row_l & 7) << 4)));
      }
#pragma unroll
    for (int dt = 0; dt < 8; ++dt) {
      const int d = dt * 16 + r16, swzd = (d & 7) << 4;
      bf16x8 w0 = *(const bf16x8*)(lwd + d * 128 + (((g4 * 8) * 2) ^ swzd));
      bf16x8 w1 = *(const bf16x8*)(lwd + d * 128 + (((32 + g4 * 8) * 2) ^ swzd));
      acc[dt][0] = MFMA16(w0, hb[0][0], acc[dt][0]);
      acc[dt][0] = MFMA16(w1, hb[0][1], acc[dt][0]);
      acc[dt][1] = MFMA16(w0, hb[1][0], acc[dt][1]);
      acc[dt][1] = MFMA16(w1, hb[1][1], acc[dt][1]);
    }
  }

  // epilogue: out = x + acc  (C'-layout: lane holds 4 consecutive d per row)
#pragma unroll
  for (int dt = 0; dt < 8; ++dt)
#pragma unroll
    for (int rt = 0; rt < 2; ++rt) {
      const size_t row = (size_t)(wrow0 + rt * 16 + r16);
      const int db = dt * 16 + g4 * 4;
      const float4 xv = *(const float4*)(x + row * 128 + db);
      float4 o;
      o.x = acc[dt][rt][0] + xv.x;
      o.y = acc[dt][rt][1] + xv.y;
      o.z = acc[dt][rt][2] + xv.z;
      o.w = acc[dt][rt][3] + xv.w;
      *(float4*)(out + row * 128 + db) = o;
    }
}

// ---------------------------------------------------------------------------

extern "C" void kernel_launch(void* const* d_in, const int* in_sizes, int n_in,
                              void* d_out, int out_size, void* d_ws, size_t ws_size,
                              hipStream_t stream) {
  (void)in_sizes; (void)n_in; (void)out_size; (void)ws_size;
  const float* x     = (const float*)d_in[0];
  const float* W     = (const float*)d_in[1];
  const float* wg    = (const float*)d_in[2];
  const float* wu    = (const float*)d_in[3];
  const float* wd    = (const float*)d_in[4];
  const float* gamma = (const float*)d_in[5];
  const float* beta  = (const float*)d_in[6];
  const float* gg    = (const float*)d_in[7];
  char* ws = (char*)d_ws;

  k_prep<<<768, 256, 0, stream>>>(W, wg, wu, wd, gg, ws);
  k_geo_ln<<<4096, 256, 0, stream>>>(x, gamma, beta, (const float*)(ws + OFF_C),
                                     (unsigned*)d_out);
  k_mlp<<<1024, 256, 0, stream>>>(x, (float*)d_out, ws);
}